// Round 13
// baseline (44.770 us; speedup 1.0000x reference)
//
#include <hip/hip_runtime.h>
#include <math.h>

// Problem: B=64, T=512, D=1024.
//   v[b,d]     = sum_e W[d,e] * x[b,T-1,e]
//   scores[b,t]= sum_d x[b,t,d] * v[b,d]          (t in 0..510)
//   alpha      = softmax_t(scores)
//   c[b,d]     = sum_t alpha[b,t] * x[b,t,d]
//   out[b]     = concat(c[b,:], x[b,T-1,:])       (64 x 2048 fp32)
//
// HISTORY:
//  R4  flash G16 prefetch                        49.3 us
//  R5-R9 fused finalize w/ __threadfence         ~200 us (L2 wb/inv -> dead end)
//  R10 flash G32 lb(256,4)                       52.0 us
//  R11 two-pass (x read twice)                   68.1 us (+16us = BW cost of 2nd pass)
//  R12 k_v 4x parallel + k_chunk lb(256,6) TLP   41.3 us  <- TLP is the lever
//  R13: k_chunk -> 8 waves/SIMD via register diet: accumulator lives in the
//       wave's cw[] LDS slice (needed there for the combine anyway).
//       VGPR target ~56 <= 64 cap of lb(256,8). Revert if >=45us (spill).

#define BB 64
#define TT 512
#define DD 1024
#define TH 511           // valid history rows: 0..510
#define GROUPS 32        // blocks per batch
#define RPW 4            // rows per wave (4 waves * 4 = 16 rows per block)

// workspace (floats):
//   v      : [BB][DD]          off 0            (65536)
//   partC  : [BB][GROUPS][DD]  off 65536        (2097152, 8 MB)
//   partML : [BB][GROUPS][2]   off 2162688      (4096)

// ---------------- kernel 1: v = x_last @ W^T -------------------------------
// 1024 blocks x 4 waves; wave = 4 d-rows (W stationary) x 4 batches.
__global__ __launch_bounds__(256, 4) void k_v(const float* __restrict__ x,
                                              const float* __restrict__ W,
                                              float* __restrict__ v) {
    const int wave = threadIdx.x >> 6;
    const int lane = threadIdx.x & 63;
    const int wg   = blockIdx.x * 4 + wave;   // 0..4095
    const int d0   = (wg >> 4) * 4;           // 256 d-quads
    const int bg   = wg & 15;                 // 16 batch-groups of 4

    float4 w4[4][4];
#pragma unroll
    for (int k = 0; k < 4; ++k)
#pragma unroll
        for (int j = 0; j < 4; ++j)
            w4[k][j] = *(const float4*)(W + (size_t)(d0 + k) * DD + j * 256 + lane * 4);

    float res = 0.f;                          // lanes 0..15: (b=bg*4+(l>>2), d=d0+(l&3))
#pragma unroll
    for (int i = 0; i < 4; ++i) {
        const int b = bg * 4 + i;
        const float* xl = x + ((size_t)b * TT + (TT - 1)) * DD;
        float4 x4[4];
#pragma unroll
        for (int j = 0; j < 4; ++j)
            x4[j] = *(const float4*)(xl + j * 256 + lane * 4);
        float p[4];
#pragma unroll
        for (int k = 0; k < 4; ++k)
            p[k] = w4[k][0].x * x4[0].x + w4[k][0].y * x4[0].y + w4[k][0].z * x4[0].z + w4[k][0].w * x4[0].w
                 + w4[k][1].x * x4[1].x + w4[k][1].y * x4[1].y + w4[k][1].z * x4[1].z + w4[k][1].w * x4[1].w
                 + w4[k][2].x * x4[2].x + w4[k][2].y * x4[2].y + w4[k][2].z * x4[2].z + w4[k][2].w * x4[2].w
                 + w4[k][3].x * x4[3].x + w4[k][3].y * x4[3].y + w4[k][3].z * x4[3].z + w4[k][3].w * x4[3].w;
#pragma unroll
        for (int mm = 1; mm < 64; mm <<= 1) {
#pragma unroll
            for (int k = 0; k < 4; ++k) p[k] += __shfl_xor(p[k], mm, 64);
        }
#pragma unroll
        for (int k = 0; k < 4; ++k)
            if (lane == i * 4 + k) res = p[k];
    }
    if (lane < 16)
        v[(size_t)(bg * 4 + (lane >> 2)) * DD + d0 + (lane & 3)] = res;
}

// ---------------- kernel 2: flash chunk, acc in LDS, 8 waves/SIMD ----------
// 2048 blocks (64 b x 32 groups), 256 thr. Wave: 4 rows online softmax;
// per-wave accumulator is its cw[wave] LDS slice (register diet -> lb(256,8)).
__global__ __launch_bounds__(256, 8) void k_chunk(const float* __restrict__ x,
                                                  const float* __restrict__ v,
                                                  float* __restrict__ partC,
                                                  float* __restrict__ partML) {
    __shared__ float cw[4][DD];               // per-wave accumulator + combine (16 KB)
    __shared__ float cml[4][2];

    const int b    = blockIdx.x >> 5;         // / GROUPS
    const int g    = blockIdx.x & (GROUPS - 1);
    const int wave = threadIdx.x >> 6;
    const int lane = threadIdx.x & 63;
    const int r0   = g * 16 + wave * RPW;     // <= 508
    const int col  = lane * 4;

    const float* xb = x + (size_t)b * TT * DD;
    const float* vb = v + (size_t)b * DD + col;
    const float4 vv0 = *(const float4*)(vb);
    const float4 vv1 = *(const float4*)(vb + 256);
    const float4 vv2 = *(const float4*)(vb + 512);
    const float4 vv3 = *(const float4*)(vb + 768);

    float* aw = &cw[wave][0];                 // this wave's accumulator slice
    {
        const float4 z4 = make_float4(0.f, 0.f, 0.f, 0.f);
        *(float4*)(aw + col)       = z4;
        *(float4*)(aw + 256 + col) = z4;
        *(float4*)(aw + 512 + col) = z4;
        *(float4*)(aw + 768 + col) = z4;
    }

    float m = -INFINITY, l = 0.f;

#pragma unroll
    for (int i = 0; i < RPW; ++i) {
        const int r  = r0 + i;
        const int rc = min(r, TH - 1);        // clamped addr; masked via score
        const float* p = xb + (size_t)rc * DD + col;
        const float4 x0 = *(const float4*)(p);
        const float4 x1 = *(const float4*)(p + 256);
        const float4 x2 = *(const float4*)(p + 512);
        const float4 x3 = *(const float4*)(p + 768);

        float s = vv0.x * x0.x + vv0.y * x0.y + vv0.z * x0.z + vv0.w * x0.w
                + vv1.x * x1.x + vv1.y * x1.y + vv1.z * x1.z + vv1.w * x1.w
                + vv2.x * x2.x + vv2.y * x2.y + vv2.z * x2.z + vv2.w * x2.w
                + vv3.x * x3.x + vv3.y * x3.y + vv3.z * x3.z + vv3.w * x3.w;
#pragma unroll
        for (int mm = 1; mm < 64; mm <<= 1) s += __shfl_xor(s, mm, 64);
        if (r >= TH) s = -INFINITY;           // invalid tail row -> e = 0

        const float mnew = fmaxf(m, s);
        if (mnew > m) {                        // wave-uniform; fires <=2x typically
            const float sc = __expf(m - mnew); // first iter: exp(-inf)=0
            float4 t0 = *(float4*)(aw + col);
            float4 t1 = *(float4*)(aw + 256 + col);
            float4 t2 = *(float4*)(aw + 512 + col);
            float4 t3 = *(float4*)(aw + 768 + col);
            t0.x *= sc; t0.y *= sc; t0.z *= sc; t0.w *= sc;
            t1.x *= sc; t1.y *= sc; t1.z *= sc; t1.w *= sc;
            t2.x *= sc; t2.y *= sc; t2.z *= sc; t2.w *= sc;
            t3.x *= sc; t3.y *= sc; t3.z *= sc; t3.w *= sc;
            *(float4*)(aw + col)       = t0;
            *(float4*)(aw + 256 + col) = t1;
            *(float4*)(aw + 512 + col) = t2;
            *(float4*)(aw + 768 + col) = t3;
            l *= sc; m = mnew;
        }
        const float e = __expf(s - m);
        l += e;
        {
            float4 a0 = *(float4*)(aw + col);
            float4 a1 = *(float4*)(aw + 256 + col);
            float4 a2 = *(float4*)(aw + 512 + col);
            float4 a3 = *(float4*)(aw + 768 + col);
            a0.x += e * x0.x; a0.y += e * x0.y; a0.z += e * x0.z; a0.w += e * x0.w;
            a1.x += e * x1.x; a1.y += e * x1.y; a1.z += e * x1.z; a1.w += e * x1.w;
            a2.x += e * x2.x; a2.y += e * x2.y; a2.z += e * x2.z; a2.w += e * x2.w;
            a3.x += e * x3.x; a3.y += e * x3.y; a3.z += e * x3.z; a3.w += e * x3.w;
            *(float4*)(aw + col)       = a0;
            *(float4*)(aw + 256 + col) = a1;
            *(float4*)(aw + 512 + col) = a2;
            *(float4*)(aw + 768 + col) = a3;
        }
    }

    if (lane == 0) { cml[wave][0] = m; cml[wave][1] = l; }
    __syncthreads();

    const float M = fmaxf(fmaxf(cml[0][0], cml[1][0]), fmaxf(cml[2][0], cml[3][0]));
    const float w0 = __expf(cml[0][0] - M), w1 = __expf(cml[1][0] - M);
    const float w2 = __expf(cml[2][0] - M), w3 = __expf(cml[3][0] - M);
    const float L = w0 * cml[0][1] + w1 * cml[1][1] + w2 * cml[2][1] + w3 * cml[3][1];

    const int d0 = threadIdx.x * 4;
    const float4 s0 = *(const float4*)(&cw[0][d0]);
    const float4 s1 = *(const float4*)(&cw[1][d0]);
    const float4 s2 = *(const float4*)(&cw[2][d0]);
    const float4 s3 = *(const float4*)(&cw[3][d0]);
    float4 o;
    o.x = w0 * s0.x + w1 * s1.x + w2 * s2.x + w3 * s3.x;
    o.y = w0 * s0.y + w1 * s1.y + w2 * s2.y + w3 * s3.y;
    o.z = w0 * s0.z + w1 * s1.z + w2 * s2.z + w3 * s3.z;
    o.w = w0 * s0.w + w1 * s1.w + w2 * s2.w + w3 * s3.w;
    *(float4*)(partC + ((size_t)b * GROUPS + g) * DD + d0) = o;
    if (threadIdx.x == 0) {
        partML[((size_t)b * GROUPS + g) * 2 + 0] = M;
        partML[((size_t)b * GROUPS + g) * 2 + 1] = L;
    }
}

// ---------------- kernel 3: combine partials, divide, append x_last --------
__global__ __launch_bounds__(256) void k_final(const float* __restrict__ x,
                                               const float* __restrict__ partC,
                                               const float* __restrict__ partML,
                                               float* __restrict__ out) {
    const int b = blockIdx.x >> 2;
    const int q = blockIdx.x & 3;
    __shared__ float wgt[GROUPS];
    __shared__ float lsh;

    if (threadIdx.x < GROUPS) {
        float M = -INFINITY;
        for (int cc = 0; cc < GROUPS; ++cc)
            M = fmaxf(M, partML[((size_t)b * GROUPS + cc) * 2]);
        wgt[threadIdx.x] = __expf(partML[((size_t)b * GROUPS + threadIdx.x) * 2] - M);
    }
    __syncthreads();
    if (threadIdx.x == 0) {
        float L = 0.f;
        for (int cc = 0; cc < GROUPS; ++cc)
            L += partML[((size_t)b * GROUPS + cc) * 2 + 1] * wgt[cc];
        lsh = 1.f / L;
    }
    __syncthreads();
    const float invL = lsh;

    const int d = q * 256 + threadIdx.x;
    float acc = 0.f;
#pragma unroll 8
    for (int cc = 0; cc < GROUPS; ++cc)
        acc += wgt[cc] * partC[((size_t)b * GROUPS + cc) * DD + d];
    out[(size_t)b * 2048 + d] = acc * invL;
    out[(size_t)b * 2048 + 1024 + d] = x[((size_t)b * TT + (TT - 1)) * DD + d];
}

extern "C" void kernel_launch(void* const* d_in, const int* in_sizes, int n_in,
                              void* d_out, int out_size, void* d_ws, size_t ws_size,
                              hipStream_t stream) {
    const float* x = (const float*)d_in[0];   // (64,512,1024) fp32
    const float* W = (const float*)d_in[1];   // (1024,1024) fp32
    float* out = (float*)d_out;               // (64,2048) fp32

    float* ws     = (float*)d_ws;             // ~8.5 MB
    float* v      = ws;                                           // 65536
    float* partC  = ws + 65536;                                   // 2097152
    float* partML = ws + 65536 + (size_t)BB * GROUPS * DD;        // 4096

    k_v<<<1024, 256, 0, stream>>>(x, W, v);
    k_chunk<<<BB * GROUPS, 256, 0, stream>>>(x, v, partC, partML);
    k_final<<<BB * 4, 256, 0, stream>>>(x, partC, partML, out);
}

// Round 14
// 42.658 us; speedup vs baseline: 1.0495x; 1.0495x over previous
//
#include <hip/hip_runtime.h>
#include <math.h>

// Problem: B=64, T=512, D=1024.
//   v[b,d]     = sum_e W[d,e] * x[b,T-1,e]
//   scores[b,t]= sum_d x[b,t,d] * v[b,d]          (t in 0..510)
//   alpha      = softmax_t(scores)
//   c[b,d]     = sum_t alpha[b,t] * x[b,t,d]
//   out[b]     = concat(c[b,:], x[b,T-1,:])       (64 x 2048 fp32)
//
// HISTORY:
//  R4  flash G16 prefetch, paired rows           49.3 us
//  R5-R9 fused finalize w/ __threadfence         ~200 us (L2 wb/inv -> dead end)
//  R10 flash G32 lb(256,4)                       52.0 us
//  R11 two-pass (x read twice)                   68.1 us (+16us = 2nd pass BW)
//  R12 k_v 4x parallel + k_chunk lb(256,6) TLP   41.3 us  <- TLP lever confirmed
//  R13 acc in LDS, 8 waves/SIMD                  44.8 us  (DS RMW in dep path -> revert)
//  R14: R12 shell + paired rows: 2 independent load/dot/butterfly chains per
//       step, ONE online rescale per pair -> serial stages per wave 4->2.
//       VGPR ~78 <= 85 cap (lb(256,6)). Revert pairing if >=42us.

#define BB 64
#define TT 512
#define DD 1024
#define TH 511           // valid history rows: 0..510
#define GROUPS 32        // blocks per batch
#define RPW 4            // rows per wave (4 waves * 4 = 16 rows per block)

// workspace (floats):
//   v      : [BB][DD]          off 0            (65536)
//   partC  : [BB][GROUPS][DD]  off 65536        (2097152, 8 MB)
//   partML : [BB][GROUPS][2]   off 2162688      (4096)

// ---------------- kernel 1: v = x_last @ W^T -------------------------------
// 1024 blocks x 4 waves; wave = 4 d-rows (W stationary) x 4 batches.
__global__ __launch_bounds__(256, 4) void k_v(const float* __restrict__ x,
                                              const float* __restrict__ W,
                                              float* __restrict__ v) {
    const int wave = threadIdx.x >> 6;
    const int lane = threadIdx.x & 63;
    const int wg   = blockIdx.x * 4 + wave;   // 0..4095
    const int d0   = (wg >> 4) * 4;           // 256 d-quads
    const int bg   = wg & 15;                 // 16 batch-groups of 4

    float4 w4[4][4];
#pragma unroll
    for (int k = 0; k < 4; ++k)
#pragma unroll
        for (int j = 0; j < 4; ++j)
            w4[k][j] = *(const float4*)(W + (size_t)(d0 + k) * DD + j * 256 + lane * 4);

    float res = 0.f;                          // lanes 0..15: (b=bg*4+(l>>2), d=d0+(l&3))
#pragma unroll
    for (int i = 0; i < 4; ++i) {
        const int b = bg * 4 + i;
        const float* xl = x + ((size_t)b * TT + (TT - 1)) * DD;
        float4 x4[4];
#pragma unroll
        for (int j = 0; j < 4; ++j)
            x4[j] = *(const float4*)(xl + j * 256 + lane * 4);
        float p[4];
#pragma unroll
        for (int k = 0; k < 4; ++k)
            p[k] = w4[k][0].x * x4[0].x + w4[k][0].y * x4[0].y + w4[k][0].z * x4[0].z + w4[k][0].w * x4[0].w
                 + w4[k][1].x * x4[1].x + w4[k][1].y * x4[1].y + w4[k][1].z * x4[1].z + w4[k][1].w * x4[1].w
                 + w4[k][2].x * x4[2].x + w4[k][2].y * x4[2].y + w4[k][2].z * x4[2].z + w4[k][2].w * x4[2].w
                 + w4[k][3].x * x4[3].x + w4[k][3].y * x4[3].y + w4[k][3].z * x4[3].z + w4[k][3].w * x4[3].w;
#pragma unroll
        for (int mm = 1; mm < 64; mm <<= 1) {
#pragma unroll
            for (int k = 0; k < 4; ++k) p[k] += __shfl_xor(p[k], mm, 64);
        }
#pragma unroll
        for (int k = 0; k < 4; ++k)
            if (lane == i * 4 + k) res = p[k];
    }
    if (lane < 16)
        v[(size_t)(bg * 4 + (lane >> 2)) * DD + d0 + (lane & 3)] = res;
}

// ---------------- kernel 2: flash chunk, paired rows, 6 waves/SIMD ---------
// 2048 blocks (64 b x 32 groups), 256 thr. Wave: 4 rows as 2 pairs; within a
// pair the two load/dot/butterfly chains are independent; one online
// rescale+accumulate per pair. Registers only; named scalars (R5-R9 lesson).
__global__ __launch_bounds__(256, 6) void k_chunk(const float* __restrict__ x,
                                                  const float* __restrict__ v,
                                                  float* __restrict__ partC,
                                                  float* __restrict__ partML) {
    __shared__ float cw[4][DD];               // 16 KB combine buffer
    __shared__ float cml[4][2];

    const int b    = blockIdx.x >> 5;         // / GROUPS
    const int g    = blockIdx.x & (GROUPS - 1);
    const int wave = threadIdx.x >> 6;
    const int lane = threadIdx.x & 63;
    const int r0   = g * 16 + wave * RPW;     // <= 508
    const int col  = lane * 4;

    const float* xb = x + (size_t)b * TT * DD;
    const float* vb = v + (size_t)b * DD + col;
    const float4 vv0 = *(const float4*)(vb);
    const float4 vv1 = *(const float4*)(vb + 256);
    const float4 vv2 = *(const float4*)(vb + 512);
    const float4 vv3 = *(const float4*)(vb + 768);

    float m = -INFINITY, l = 0.f;
    float4 acc0 = make_float4(0,0,0,0), acc1 = make_float4(0,0,0,0);
    float4 acc2 = make_float4(0,0,0,0), acc3 = make_float4(0,0,0,0);

#pragma unroll
    for (int pp = 0; pp < RPW / 2; ++pp) {
        const int ra = r0 + 2 * pp;
        const int rb = ra + 1;
        const int rca = min(ra, TH - 1);      // clamped addr; masked via score
        const int rcb = min(rb, TH - 1);
        const float* pa = xb + (size_t)rca * DD + col;
        const float* pb = xb + (size_t)rcb * DD + col;
        const float4 xa0 = *(const float4*)(pa);
        const float4 xa1 = *(const float4*)(pa + 256);
        const float4 xa2 = *(const float4*)(pa + 512);
        const float4 xa3 = *(const float4*)(pa + 768);
        const float4 xb0 = *(const float4*)(pb);
        const float4 xb1 = *(const float4*)(pb + 256);
        const float4 xb2 = *(const float4*)(pb + 512);
        const float4 xb3 = *(const float4*)(pb + 768);

        float s0 = vv0.x * xa0.x + vv0.y * xa0.y + vv0.z * xa0.z + vv0.w * xa0.w
                 + vv1.x * xa1.x + vv1.y * xa1.y + vv1.z * xa1.z + vv1.w * xa1.w
                 + vv2.x * xa2.x + vv2.y * xa2.y + vv2.z * xa2.z + vv2.w * xa2.w
                 + vv3.x * xa3.x + vv3.y * xa3.y + vv3.z * xa3.z + vv3.w * xa3.w;
        float s1 = vv0.x * xb0.x + vv0.y * xb0.y + vv0.z * xb0.z + vv0.w * xb0.w
                 + vv1.x * xb1.x + vv1.y * xb1.y + vv1.z * xb1.z + vv1.w * xb1.w
                 + vv2.x * xb2.x + vv2.y * xb2.y + vv2.z * xb2.z + vv2.w * xb2.w
                 + vv3.x * xb3.x + vv3.y * xb3.y + vv3.z * xb3.z + vv3.w * xb3.w;
#pragma unroll
        for (int mm = 1; mm < 64; mm <<= 1) {  // two independent butterflies
            s0 += __shfl_xor(s0, mm, 64);
            s1 += __shfl_xor(s1, mm, 64);
        }
        if (ra >= TH) s0 = -INFINITY;          // only last pair can mask
        if (rb >= TH) s1 = -INFINITY;

        const float mn = fmaxf(m, fmaxf(s0, s1));
        if (mn > m) {                          // wave-uniform branch
            const float sc = __expf(m - mn);   // first pair: exp(-inf)=0
            acc0.x *= sc; acc0.y *= sc; acc0.z *= sc; acc0.w *= sc;
            acc1.x *= sc; acc1.y *= sc; acc1.z *= sc; acc1.w *= sc;
            acc2.x *= sc; acc2.y *= sc; acc2.z *= sc; acc2.w *= sc;
            acc3.x *= sc; acc3.y *= sc; acc3.z *= sc; acc3.w *= sc;
            l *= sc; m = mn;
        }
        const float e0 = __expf(s0 - m);
        const float e1 = __expf(s1 - m);
        l += e0 + e1;
        acc0.x += e0 * xa0.x + e1 * xb0.x; acc0.y += e0 * xa0.y + e1 * xb0.y;
        acc0.z += e0 * xa0.z + e1 * xb0.z; acc0.w += e0 * xa0.w + e1 * xb0.w;
        acc1.x += e0 * xa1.x + e1 * xb1.x; acc1.y += e0 * xa1.y + e1 * xb1.y;
        acc1.z += e0 * xa1.z + e1 * xb1.z; acc1.w += e0 * xa1.w + e1 * xb1.w;
        acc2.x += e0 * xa2.x + e1 * xb2.x; acc2.y += e0 * xa2.y + e1 * xb2.y;
        acc2.z += e0 * xa2.z + e1 * xb2.z; acc2.w += e0 * xa2.w + e1 * xb2.w;
        acc3.x += e0 * xa3.x + e1 * xb3.x; acc3.y += e0 * xa3.y + e1 * xb3.y;
        acc3.z += e0 * xa3.z + e1 * xb3.z; acc3.w += e0 * xa3.w + e1 * xb3.w;
    }

    // one cross-wave combine per block
    *(float4*)(&cw[wave][0 * 256 + col]) = acc0;
    *(float4*)(&cw[wave][1 * 256 + col]) = acc1;
    *(float4*)(&cw[wave][2 * 256 + col]) = acc2;
    *(float4*)(&cw[wave][3 * 256 + col]) = acc3;
    if (lane == 0) { cml[wave][0] = m; cml[wave][1] = l; }
    __syncthreads();

    const float M = fmaxf(fmaxf(cml[0][0], cml[1][0]), fmaxf(cml[2][0], cml[3][0]));
    const float w0 = __expf(cml[0][0] - M), w1 = __expf(cml[1][0] - M);
    const float w2 = __expf(cml[2][0] - M), w3 = __expf(cml[3][0] - M);
    const float L = w0 * cml[0][1] + w1 * cml[1][1] + w2 * cml[2][1] + w3 * cml[3][1];

    const int d0 = threadIdx.x * 4;
    const float4 s0 = *(const float4*)(&cw[0][d0]);
    const float4 s1 = *(const float4*)(&cw[1][d0]);
    const float4 s2 = *(const float4*)(&cw[2][d0]);
    const float4 s3 = *(const float4*)(&cw[3][d0]);
    float4 o;
    o.x = w0 * s0.x + w1 * s1.x + w2 * s2.x + w3 * s3.x;
    o.y = w0 * s0.y + w1 * s1.y + w2 * s2.y + w3 * s3.y;
    o.z = w0 * s0.z + w1 * s1.z + w2 * s2.z + w3 * s3.z;
    o.w = w0 * s0.w + w1 * s1.w + w2 * s2.w + w3 * s3.w;
    *(float4*)(partC + ((size_t)b * GROUPS + g) * DD + d0) = o;
    if (threadIdx.x == 0) {
        partML[((size_t)b * GROUPS + g) * 2 + 0] = M;
        partML[((size_t)b * GROUPS + g) * 2 + 1] = L;
    }
}

// ---------------- kernel 3: combine partials, divide, append x_last --------
__global__ __launch_bounds__(256) void k_final(const float* __restrict__ x,
                                               const float* __restrict__ partC,
                                               const float* __restrict__ partML,
                                               float* __restrict__ out) {
    const int b = blockIdx.x >> 2;
    const int q = blockIdx.x & 3;
    __shared__ float wgt[GROUPS];
    __shared__ float lsh;

    if (threadIdx.x < GROUPS) {
        float M = -INFINITY;
        for (int cc = 0; cc < GROUPS; ++cc)
            M = fmaxf(M, partML[((size_t)b * GROUPS + cc) * 2]);
        wgt[threadIdx.x] = __expf(partML[((size_t)b * GROUPS + threadIdx.x) * 2] - M);
    }
    __syncthreads();
    if (threadIdx.x == 0) {
        float L = 0.f;
        for (int cc = 0; cc < GROUPS; ++cc)
            L += partML[((size_t)b * GROUPS + cc) * 2 + 1] * wgt[cc];
        lsh = 1.f / L;
    }
    __syncthreads();
    const float invL = lsh;

    const int d = q * 256 + threadIdx.x;
    float acc = 0.f;
#pragma unroll 8
    for (int cc = 0; cc < GROUPS; ++cc)
        acc += wgt[cc] * partC[((size_t)b * GROUPS + cc) * DD + d];
    out[(size_t)b * 2048 + d] = acc * invL;
    out[(size_t)b * 2048 + 1024 + d] = x[((size_t)b * TT + (TT - 1)) * DD + d];
}

extern "C" void kernel_launch(void* const* d_in, const int* in_sizes, int n_in,
                              void* d_out, int out_size, void* d_ws, size_t ws_size,
                              hipStream_t stream) {
    const float* x = (const float*)d_in[0];   // (64,512,1024) fp32
    const float* W = (const float*)d_in[1];   // (1024,1024) fp32
    float* out = (float*)d_out;               // (64,2048) fp32

    float* ws     = (float*)d_ws;             // ~8.5 MB
    float* v      = ws;                                           // 65536
    float* partC  = ws + 65536;                                   // 2097152
    float* partML = ws + 65536 + (size_t)BB * GROUPS * DD;        // 4096

    k_v<<<1024, 256, 0, stream>>>(x, W, v);
    k_chunk<<<BB * GROUPS, 256, 0, stream>>>(x, v, partC, partML);
    k_final<<<BB * 4, 256, 0, stream>>>(x, partC, partML, out);
}